// Round 1
// baseline (196.989 us; speedup 1.0000x reference)
//
#include <hip/hip_runtime.h>
#include <math.h>

// QueryEmb: B=4,L=512,D=512,V=32000, 4 segments of 8000, TEMP=sqrt(512).
// Equivalences: (1) masked softmax == softmax over token's own segment only;
// (2) |scores|<=~0.35 -> exp() safe without max-subtraction -> plain-sum
//     denoms and trivially split-K PV.
// R11: double-buffered BK=64 pipeline for k_qk/k_pv (T3-minimum). Unified
// A|B LDS tile [128 rows][8 granules], A in granules 0-3, B in 4-7, XOR
// swizzle position = cg ^ (row&7) (period-8 kept -> 2-way banks, free).
// Two static 16KB buffers (32KB total, occupancy unchanged at 4 blk/CU).
// Per step: ds_read ks0 -> issue next-tile gll16 -> 16 MFMA -> ds_read ks1
// -> 16 MFMA -> one __syncthreads. Staging overlaps compute; barrier rate
// per unit-K unchanged. Also early-return the c==63 row tile in k_qk
// (writes nothing). R10's fp8 everything + XCD binding kept.

constexpr int Dm   = 512;
constexpr int SEG  = 8000;
constexpr int PSTR = 8064;            // P row stride (63*128), pad rows zeroed
constexpr int NTOK = 2048;
constexpr int TIL  = 128;             // slot tile
constexpr int MAXTILES = 20;          // 2048/128 + 4 pad
constexpr int MAXSLOTS = MAXTILES * TIL;   // 2560

// ws layout (bytes)
constexpr size_t WS_DENOM = 0;                                   // 2048 f32
constexpr size_t WS_META  = 8192;                                // 8 int
constexpr size_t WS_PERM  = 8448;                                // 2560 int
constexpr size_t WS_QB8   = 32768;                               // fp8 [2560][512]
constexpr size_t WS_EB8   = WS_QB8 + (size_t)MAXSLOTS * Dm;      // fp8 [32000][512]
constexpr size_t WS_OACC  = WS_EB8 + (size_t)32000 * Dm;         // bf16 [8][512][2560]
constexpr size_t WS_ET8   = WS_OACC + (size_t)8 * Dm * MAXSLOTS * 2;  // fp8 [512][32000]
constexpr size_t WS_P8    = WS_ET8 + (size_t)Dm * 32000;         // fp8 [2560][8064]
// total ~75.7 MB (< proven 104 MB)

typedef __attribute__((ext_vector_type(4))) float f32x4;

static __device__ __forceinline__ ushort f2bf(float f) {
    union { float f; unsigned u; } v; v.f = f;
    unsigned r = v.u + 0x7FFF + ((v.u >> 16) & 1);   // RNE
    return (ushort)(r >> 16);
}
static __device__ __forceinline__ float bf2f(ushort u) {
    union { unsigned u; float f; } v; v.u = ((unsigned)u) << 16;
    return v.f;
}
// pack 4 floats -> 4 OCP fp8 e4m3 bytes (byte0 = a .. byte3 = d)
static __device__ __forceinline__ int pack_fp8x4(float a, float b, float c, float d) {
    int r = __builtin_amdgcn_cvt_pk_fp8_f32(a, b, 0, false);
    r = __builtin_amdgcn_cvt_pk_fp8_f32(c, d, r, true);
    return r;
}

// async global(16B/lane) -> LDS(wave-uniform base + lane*16)
static __device__ __forceinline__ void gll16(const void* g, void* l) {
    __builtin_amdgcn_global_load_lds(
        (const __attribute__((address_space(1))) unsigned int*)g,
        (__attribute__((address_space(3))) unsigned int*)l, 16, 0, 0);
}

// ---- K1: sort tokens by rank into 128-padded slot regions (1 block) ----
__global__ __launch_bounds__(256)
void k_prep(const int* __restrict__ xr, int* __restrict__ meta, int* __restrict__ perm,
            float* __restrict__ denom) {
    __shared__ int cnt[4], base[5], cur[4];
    const int tid = threadIdx.x;
    if (tid < 4) { cnt[tid] = 0; cur[tid] = 0; }
    __syncthreads();
    for (int t = tid; t < NTOK; t += 256) {
        atomicAdd(&cnt[xr[t]], 1);
        denom[t] = 0.f;
    }
    __syncthreads();
    if (tid == 0) {
        base[0] = 0;
        for (int r = 0; r < 4; ++r) base[r+1] = base[r] + ((cnt[r] + TIL - 1) / TIL) * TIL;
        for (int r = 0; r < 5; ++r) meta[r] = base[r];
    }
    __syncthreads();
    for (int s = tid; s < MAXSLOTS; s += 256) perm[s] = -1;
    __syncthreads();
    for (int t = tid; t < NTOK; t += 256) {
        int r = xr[t];
        perm[base[r] + atomicAdd(&cur[r], 1)] = t;
    }
}

// ---- K2: emb fp32 -> EB8 fp8 row-major + ET8 fp8 transposed ----
// Tile 128 rows x 64 d. sT granule (d, gr): 16 rows of one d (16 B) at
// (d*8 + (gr ^ (d&7)))*16; write half-granules (8 rows, b64) per thread.
__global__ __launch_bounds__(256)
void k_conv(const float* __restrict__ emb, unsigned char* __restrict__ EB8,
            unsigned char* __restrict__ ET8) {
    __shared__ unsigned char sT[64 * 8 * 16];   // 8 KB
    const int tid = threadIdx.x;
    const int r0 = blockIdx.x * 128, d0 = blockIdx.y * 64;
    {
        const int dq = tid & 15, ro = tid >> 4;     // 4-d group, 8-row group
        int p[8];
        #pragma unroll
        for (int i = 0; i < 8; ++i) {
            float4 v = *(const float4*)(emb + (size_t)(r0 + ro*8 + i) * Dm + d0 + dq*4);
            p[i] = pack_fp8x4(v.x, v.y, v.z, v.w);
            *(int*)(EB8 + (size_t)(r0 + ro*8 + i) * Dm + d0 + dq*4) = p[i];
        }
        const int gr = ro >> 1, half = ro & 1;
        #pragma unroll
        for (int j = 0; j < 4; ++j) {               // per d: pack 8 row-bytes
            const int d = dq*4 + j;
            unsigned long long t = 0;
            #pragma unroll
            for (int i = 0; i < 8; ++i)
                t |= ((unsigned long long)((p[i] >> (8*j)) & 0xff)) << (8*i);
            *(unsigned long long*)(sT + (d*8 + (gr ^ (d & 7))) * 16 + half * 8) = t;
        }
    }
    __syncthreads();
    {
        const int d = tid >> 2, rq = tid & 3;
        unsigned char* dst = ET8 + (size_t)(d0 + d) * 32000 + r0;
        #pragma unroll
        for (int b = 0; b < 2; ++b) {
            const int gr = rq * 2 + b;
            *(uint4*)(dst + gr * 16) = *(const uint4*)(sT + (d*8 + (gr ^ (d & 7))) * 16);
        }
    }
}

// ---- K2b: gather Q -> Qb8 fp8 [2560 slots][512] (pad slots zeroed) ----
__global__ __launch_bounds__(256)
void k_qb(const float* __restrict__ q, const int* __restrict__ perm,
          unsigned char* __restrict__ Qb8) {
    const int slot = blockIdx.x * 8 + (threadIdx.x >> 5);
    const int ln = threadIdx.x & 31;
    const int tok = perm[slot];
    #pragma unroll
    for (int j = 0; j < 4; ++j) {
        const int c4 = ln + j * 32;
        int p = 0;
        if (tok >= 0) {
            float4 v = ((const float4*)q)[(size_t)tok * 128 + c4];
            p = pack_fp8x4(v.x, v.y, v.z, v.w);
        }
        ((int*)(Qb8 + (size_t)slot * Dm))[c4] = p;
    }
}

// One pipeline step: compute tile in CUR (BK=64 = 2 k-chunks of 32),
// stage tile TI into NXT between the ks0 ds_reads and the ks0 MFMAs.
// Requires locals: pre[4], w, rh, th, quad, l15, acc.
#define GSTEP(CUR, NXT, TI, DOSTAGE)                                           \
    {                                                                          \
        long A[4], B[4];                                                       \
        const int cg0 = (quad >> 1), ho = (quad & 1) * 8;                      \
        _Pragma("unroll")                                                      \
        for (int m = 0; m < 4; ++m) {                                          \
            const int row = rh*64 + m*16 + l15;                                \
            A[m] = *(const long*)(CUR + row*128 + ((cg0) ^ (row & 7))*16 + ho);\
        }                                                                      \
        _Pragma("unroll")                                                      \
        for (int n = 0; n < 4; ++n) {                                          \
            const int row = th*64 + n*16 + l15;                                \
            B[n] = *(const long*)(CUR + row*128 + ((4 + cg0) ^ (row & 7))*16 + ho);\
        }                                                                      \
        if (DOSTAGE) {                                                         \
            _Pragma("unroll")                                                  \
            for (int i = 0; i < 4; ++i)                                        \
                gll16(pre[i] + (TI)*64, NXT + (w*256 + i*64)*16);              \
        }                                                                      \
        _Pragma("unroll")                                                      \
        for (int m = 0; m < 4; ++m)                                            \
            _Pragma("unroll")                                                  \
            for (int n = 0; n < 4; ++n)                                        \
                acc[m][n] = __builtin_amdgcn_mfma_f32_16x16x32_fp8_fp8(A[m], B[n], acc[m][n], 0, 0, 0); \
        _Pragma("unroll")                                                      \
        for (int m = 0; m < 4; ++m) {                                          \
            const int row = rh*64 + m*16 + l15;                                \
            A[m] = *(const long*)(CUR + row*128 + ((2 + cg0) ^ (row & 7))*16 + ho);\
        }                                                                      \
        _Pragma("unroll")                                                      \
        for (int n = 0; n < 4; ++n) {                                          \
            const int row = th*64 + n*16 + l15;                                \
            B[n] = *(const long*)(CUR + row*128 + ((6 + cg0) ^ (row & 7))*16 + ho);\
        }                                                                      \
        _Pragma("unroll")                                                      \
        for (int m = 0; m < 4; ++m)                                            \
            _Pragma("unroll")                                                  \
            for (int n = 0; n < 4; ++n)                                        \
                acc[m][n] = __builtin_amdgcn_mfma_f32_16x16x32_fp8_fp8(A[m], B[n], acc[m][n], 0, 0, 0); \
        __syncthreads();                                                       \
    }

// ---- K3: S^T = E.Q^T fp8, dbuf BK=64; XCD-bound row-tiles; exp -> P8 ----
__global__ __launch_bounds__(256, 4)
void k_qk(const unsigned char* __restrict__ EB8, const unsigned char* __restrict__ Qb8,
          const int* __restrict__ meta, const int* __restrict__ perm,
          float* __restrict__ denom, unsigned char* __restrict__ P8) {
    __shared__ unsigned char s0[128 * 128];   // 16 KB unified A|B tile (BK=64)
    __shared__ unsigned char s1[128 * 128];   // double buffer
    const int tid = threadIdx.x, lane = tid & 63, w = tid >> 6;
    const int g    = blockIdx.x & 7;              // XCD group
    const int rest = blockIdx.x >> 3;
    const int rt_local = rest / MAXTILES;         // 0..7
    const int tt       = rest % MAXTILES;
    const int c = g * 8 + rt_local;               // row-tile 0..63
    const int slot0 = tt * TIL;
    const int b1 = meta[1], b2 = meta[2], b3 = meta[3], b4 = meta[4];
    if (slot0 >= b4) return;
    const int row0 = c * 128;
    if (row0 >= PSTR) return;                     // c==63: provably writes nothing
    const int rank = (slot0 >= b1) + (slot0 >= b2) + (slot0 >= b3);

    // per-thread source pointers for the 4 staged granules (16 B each).
    // granule gg: LDS row r = gg>>3, unit u = gg&7; content cg = u ^ (r&7):
    // cg<4 -> A (EB8 row, k-granule cg), cg>=4 -> B (Qb8 slot row, k-granule cg-4)
    const unsigned char* pre[4];
    #pragma unroll
    for (int i = 0; i < 4; ++i) {
        const int gg = w * 256 + i * 64 + lane;
        const int r = gg >> 3, u = gg & 7, cg = u ^ (r & 7);
        if (cg < 4) {
            int grow = row0 + r;
            if (grow >= SEG) grow = SEG - 1;      // clamp; outputs masked
            pre[i] = EB8 + (size_t)rank * SEG * Dm + (size_t)grow * Dm + cg * 16;
        } else {
            pre[i] = Qb8 + (size_t)(slot0 + r) * Dm + (cg - 4) * 16;
        }
    }
    const int rh = w >> 1, th = w & 1, quad = lane >> 4, l15 = lane & 15;
    const float invT = 0.04419417382415922f;   // 1/sqrt(512)

    f32x4 acc[4][4] = {};
    #pragma unroll
    for (int i = 0; i < 4; ++i)                   // prologue: stage tile 0
        gll16(pre[i], s0 + (w * 256 + i * 64) * 16);
    __syncthreads();
    GSTEP(s0, s1, 1, true)
    GSTEP(s1, s0, 2, true)
    GSTEP(s0, s1, 3, true)
    GSTEP(s1, s0, 4, true)
    GSTEP(s0, s1, 5, true)
    GSTEP(s1, s0, 6, true)
    GSTEP(s0, s1, 7, true)
    GSTEP(s1, s0, 8, false)

    float dsum[4] = {0.f, 0.f, 0.f, 0.f};
    #pragma unroll
    for (int m = 0; m < 4; ++m) {
        const int r4 = row0 + rh*64 + m*16 + quad*4;
        if (r4 < SEG) {
            #pragma unroll
            for (int n = 0; n < 4; ++n) {
                float e0 = __expf(acc[m][n][0] * invT);
                float e1 = __expf(acc[m][n][1] * invT);
                float e2 = __expf(acc[m][n][2] * invT);
                float e3 = __expf(acc[m][n][3] * invT);
                const int slot = slot0 + th*64 + n*16 + l15;
                *(int*)(P8 + (size_t)slot * PSTR + r4) = pack_fp8x4(e0, e1, e2, e3);
                dsum[n] += e0 + e1 + e2 + e3;
            }
        } else if (r4 < PSTR) {                // zero the pad rows (k_pv tail)
            #pragma unroll
            for (int n = 0; n < 4; ++n) {
                const int slot = slot0 + th*64 + n*16 + l15;
                *(int*)(P8 + (size_t)slot * PSTR + r4) = 0;
            }
        }
    }
    #pragma unroll
    for (int n = 0; n < 4; ++n) {
        float s = dsum[n];
        s += __shfl_xor(s, 16, 64);
        s += __shfl_xor(s, 32, 64);
        if (quad == 0) {
            const int tok = perm[slot0 + th*64 + n*16 + l15];
            if (tok >= 0) atomicAdd(denom + tok, s);
        }
    }
}

// ---- K4: O^T = E^T.P^T fp8, dbuf BK=64; K-split z = XCD; bf16 partials ----
__global__ __launch_bounds__(256, 4)
void k_pv(const unsigned char* __restrict__ ET8, const unsigned char* __restrict__ P8,
          const int* __restrict__ meta, ushort* __restrict__ Oacc) {
    __shared__ unsigned char s0[128 * 128];
    __shared__ unsigned char s1[128 * 128];
    const int tid = threadIdx.x, lane = tid & 63, w = tid >> 6;
    const int z    = blockIdx.x & 7;              // K-split == XCD group
    const int rest = blockIdx.x >> 3;
    const int dt   = rest / MAXTILES;             // d-tile 0..3
    const int tt   = rest % MAXTILES;
    const int slot0 = tt * TIL;
    const int b1 = meta[1], b2 = meta[2], b3 = meta[3], b4 = meta[4];
    if (slot0 >= b4) return;
    const int rank = (slot0 >= b1) + (slot0 >= b2) + (slot0 >= b3);
    const int d0 = dt * 128;
    const int kstart = z * 1024;
    const int nit = (z == 7) ? 14 : 16;           // BK=64: 7*16+14 = 126 -> 8064 rows

    const unsigned char* pre[4];
    #pragma unroll
    for (int i = 0; i < 4; ++i) {
        const int gg = w * 256 + i * 64 + lane;
        const int r = gg >> 3, u = gg & 7, cg = u ^ (r & 7);
        if (cg < 4)   // v>=8000 reads x P8-pad 0
            pre[i] = ET8 + (size_t)(d0 + r) * 32000 + (size_t)rank * SEG + kstart + cg * 16;
        else
            pre[i] = P8 + (size_t)(slot0 + r) * PSTR + kstart + (cg - 4) * 16;
    }
    const int rh = w >> 1, th = w & 1, quad = lane >> 4, l15 = lane & 15;

    f32x4 acc[4][4] = {};
    #pragma unroll
    for (int i = 0; i < 4; ++i)                   // prologue: stage tile 0
        gll16(pre[i], s0 + (w * 256 + i * 64) * 16);
    __syncthreads();
    const int nit2 = nit >> 1;
    for (int it2 = 0; it2 < nit2 - 1; ++it2) {
        GSTEP(s0, s1, 2*it2 + 1, true)
        GSTEP(s1, s0, 2*it2 + 2, true)
    }
    GSTEP(s0, s1, nit - 1, true)
    GSTEP(s1, s0, nit, false)

    ushort* Oz = Oacc + (size_t)z * Dm * MAXSLOTS;
    #pragma unroll
    for (int m = 0; m < 4; ++m) {
        const int d4 = d0 + rh*64 + m*16 + quad*4;
        #pragma unroll
        for (int n = 0; n < 4; ++n) {
            const int slot = slot0 + th*64 + n*16 + l15;
            #pragma unroll
            for (int j = 0; j < 4; ++j)
                Oz[(size_t)(d4 + j) * MAXSLOTS + slot] = f2bf(acc[m][n][j]);
        }
    }
}

// ---- K5: out[tok][d] = (sum_z Oacc[z][d][slot]) / denom + q ----
__global__ __launch_bounds__(256)
void k_final(const float* __restrict__ q, const int* __restrict__ meta,
             const int* __restrict__ perm, const float* __restrict__ denom,
             const ushort* __restrict__ Oacc, float* __restrict__ out) {
    const int d = blockIdx.x;
    const int ns = meta[4];
    for (int s = threadIdx.x; s < ns; s += 256) {
        const int tok = perm[s];
        if (tok < 0) continue;
        float v = 0.f;
        #pragma unroll
        for (int z = 0; z < 8; ++z)
            v += bf2f(Oacc[((size_t)z * Dm + d) * MAXSLOTS + s]);
        out[(size_t)tok * Dm + d] = v / denom[tok] + q[(size_t)tok * Dm + d];
    }
}

extern "C" void kernel_launch(void* const* d_in, const int* in_sizes, int n_in,
                              void* d_out, int out_size, void* d_ws, size_t ws_size,
                              hipStream_t stream) {
    const float* q   = (const float*)d_in[0];
    const int*   xr  = (const int*)d_in[1];
    const float* emb = (const float*)d_in[2];
    float* out = (float*)d_out;
    char* ws = (char*)d_ws;

    float*  denom        = (float*)(ws + WS_DENOM);
    int*    meta         = (int*)(ws + WS_META);
    int*    perm         = (int*)(ws + WS_PERM);
    unsigned char* Qb8   = (unsigned char*)(ws + WS_QB8);
    unsigned char* EB8   = (unsigned char*)(ws + WS_EB8);
    ushort* Oacc         = (ushort*)(ws + WS_OACC);
    unsigned char* ET8   = (unsigned char*)(ws + WS_ET8);
    unsigned char* P8    = (unsigned char*)(ws + WS_P8);

    k_prep<<<1, 256, 0, stream>>>(xr, meta, perm, denom);
    k_conv<<<dim3(250, 8), 256, 0, stream>>>(emb, EB8, ET8);
    k_qb<<<MAXSLOTS / 8, 256, 0, stream>>>(q, perm, Qb8);
    k_qk<<<8 * 8 * MAXTILES, 256, 0, stream>>>(EB8, Qb8, meta, perm, denom, P8);
    k_pv<<<8 * 4 * MAXTILES, 256, 0, stream>>>(ET8, P8, meta, Oacc);
    k_final<<<Dm, 256, 0, stream>>>(q, meta, perm, denom, Oacc, out);
}